// Round 5
// baseline (2709.887 us; speedup 1.0000x reference)
//
#include <hip/hip_runtime.h>
#include <hip/hip_bf16.h>
#include <math.h>
#include <string.h>

#define L_TOK 16384
#define D_INP 256
#define D_MOD 768
#define D_FF  1536
#define N_LAYER 8
#define S_T 64
#define S_G 256
#define EPSV 1e-5f

typedef short bf16x8 __attribute__((ext_vector_type(8)));
typedef float f32x4 __attribute__((ext_vector_type(4)));
typedef __hip_bfloat16 bf16;
typedef unsigned int u32;
typedef unsigned short u16;

__device__ __forceinline__ float fsigmoid(float z) { return 1.0f / (1.0f + __expf(-z)); }

__device__ __forceinline__ u16 f2bf(float f) {
  __hip_bfloat16 h = __float2bfloat16(f);
  u16 r; memcpy(&r, &h, 2); return r;
}
__device__ __forceinline__ float bf2f(u16 v) {
  u32 x = ((u32)v) << 16; float f; memcpy(&f, &x, 4); return f;
}

// async global->LDS, 16B per lane. LDS dest = (wave-uniform base) + lane*16.
__device__ __forceinline__ void glds16(const short* g, short* l) {
  __builtin_amdgcn_global_load_lds(
      (const __attribute__((address_space(1))) unsigned int*)(g),
      (__attribute__((address_space(3))) unsigned int*)(l), 16, 0, 0);
}

// ---------------- f32 -> bf16, vectorized (n % 4 == 0) ----------------
__global__ void k_f32_to_bf16v(const float4* __restrict__ src, ushort4* __restrict__ dst, int n4) {
  int i = blockIdx.x * blockDim.x + threadIdx.x;
  if (i < n4) {
    float4 v = src[i];
    ushort4 o; o.x = f2bf(v.x); o.y = f2bf(v.y); o.z = f2bf(v.z); o.w = f2bf(v.w);
    dst[i] = o;
  }
}

// ------- transpose+convert: src [z][R,C] f32 -> dst [z][C,R] bf16 (strided per z) ----
// R, C multiples of 32. block (32,8), grid (C/32, R/32, NZ)
__global__ void k_transpose_bf16(const float* __restrict__ src, bf16* __restrict__ dst,
                                 int R, int C, size_t sstride, size_t dstride) {
  __shared__ float tile[32][33];
  const float* s = src + (size_t)blockIdx.z * sstride;
  bf16* d = dst + (size_t)blockIdx.z * dstride;
  int r0 = blockIdx.y * 32, c0 = blockIdx.x * 32;
  int tx = threadIdx.x, ty = threadIdx.y;
#pragma unroll
  for (int i = ty; i < 32; i += 8)
    tile[i][tx] = s[(size_t)(r0 + i) * C + (c0 + tx)];
  __syncthreads();
#pragma unroll
  for (int i = ty; i < 32; i += 8)
    d[(size_t)(c0 + i) * R + (r0 + tx)] = __float2bfloat16(tile[tx][i]);
}

// ---------------- LayerNorm over D_MOD=768: 4 waves/block, one wave per row ----------
template<bool BF16OUT>
__global__ __launch_bounds__(256) void k_layernorm(const float* __restrict__ x,
    const float* __restrict__ g, const float* __restrict__ b, void* __restrict__ outp) {
  int wv = threadIdx.x >> 6, lane = threadIdx.x & 63;
  int row = blockIdx.x * 4 + wv;
  const float4* xr = (const float4*)(x + (size_t)row * D_MOD);
  float4 v[3];
  float s = 0.f, s2 = 0.f;
#pragma unroll
  for (int j = 0; j < 3; j++) {
    v[j] = xr[j * 64 + lane];
    s  += v[j].x + v[j].y + v[j].z + v[j].w;
    s2 += v[j].x*v[j].x + v[j].y*v[j].y + v[j].z*v[j].z + v[j].w*v[j].w;
  }
#pragma unroll
  for (int o = 32; o >= 1; o >>= 1) {
    s  += __shfl_xor(s, o, 64);
    s2 += __shfl_xor(s2, o, 64);
  }
  float mu = s * (1.0f / (float)D_MOD);
  float var = s2 * (1.0f / (float)D_MOD) - mu * mu;
  float rv = 1.0f / sqrtf(var + EPSV);
  const float4* g4 = (const float4*)g;
  const float4* b4 = (const float4*)b;
#pragma unroll
  for (int j = 0; j < 3; j++) {
    int f = j * 64 + lane;
    float4 gg = g4[f], bb = b4[f], ov;
    ov.x = (v[j].x - mu) * rv * gg.x + bb.x;
    ov.y = (v[j].y - mu) * rv * gg.y + bb.y;
    ov.z = (v[j].z - mu) * rv * gg.z + bb.z;
    ov.w = (v[j].w - mu) * rv * gg.w + bb.w;
    if (BF16OUT) {
      ushort4 o4; o4.x = f2bf(ov.x); o4.y = f2bf(ov.y); o4.z = f2bf(ov.z); o4.w = f2bf(ov.w);
      ((ushort4*)outp)[(size_t)row * 192 + f] = o4;
    } else {
      ((float4*)outp)[(size_t)row * 192 + f] = ov;
    }
  }
}

// ---------------- bf16 MFMA GEMM: 3-stage glds pipeline, partial-vmcnt barriers -----
// C[16384,N] = A[16384,K] * Bt[N,K]^T (+bias, fused epilogue). 128x128 tile, BK=32,
// 256 thr (2x2 waves of 64x64). Each wave issues exactly 4 glds/iter; loop-top
// barrier waits vmcnt(8) so the 2 younger tiles stay IN FLIGHT across the barrier
// (AITER pattern). Tail kept uniform with wrap-around dummy glds into dead buffers.
// XOR-swizzled LDS chunks (0 bank conflicts). XCD band swizzle for L2 locality.
// MODE: 0 bias; 2 silu; 3 bias+residual; 4 split u|gate (bias / sigmoid+bias2)
template<int MODE, bool OUTBF16>
__global__ __launch_bounds__(256, 4) void k_gemm128(
    const short* __restrict__ A, const short* __restrict__ Bt,
    const float* __restrict__ bias, const float* __restrict__ bias2,
    const float* __restrict__ res, void* __restrict__ outp, void* __restrict__ outp2,
    int N, int K, int ncol)
{
  __shared__ short As[3][128 * 32];
  __shared__ short Bs[3][128 * 32];
  const int tid = threadIdx.x;
  const int lane = tid & 63, w = tid >> 6;
  const int wr = w >> 1, wc = w & 1;
  const int l16 = lane & 15, qd = lane >> 4;

  // XCD band swizzle: xcd = bid&7 owns rows [xcd*16, xcd*16+16), sweeps cols fastest.
  const int b = blockIdx.x;
  const int xcd = b & 7, t = b >> 3;
  const int m0 = (xcd * 16 + t / ncol) * 128;
  const int n0 = (t % ncol) * 128;

  // staging: wave w covers tile rows w*32..+31 (rows sr, sr+16; chunk sc of 4)
  const int sr = lane >> 2, sc = lane & 3;
  const int ar = w * 32 + sr;
  const int acx = sc ^ ((ar >> 1) & 3);          // XOR chunk swizzle (same for ar, ar+16)
  const short* ag0 = A  + (size_t)(m0 + ar) * K + acx * 8;
  const short* ag1 = ag0 + (size_t)16 * K;
  const short* bg0 = Bt + (size_t)(n0 + ar) * K + acx * 8;
  const short* bg1 = bg0 + (size_t)16 * K;

  // fragment read: logical chunk qd of row r lives at physical chunk qd^((r>>1)&3)
  const int fo = (qd ^ ((l16 >> 1) & 3)) * 8 + l16 * 32;

  f32x4 acc[4][4];
#pragma unroll
  for (int i = 0; i < 4; i++)
#pragma unroll
    for (int j = 0; j < 4; j++) acc[i][j] = (f32x4){0.f, 0.f, 0.f, 0.f};

  const int NI = K >> 5;            // K/32 tiles (>= 3 for all shapes here)
  // per-wave glds issue for tile `ti` into stage `st` (4 glds, wave-uniform LDS base)
  auto issue = [&](int ti, int st) {
    const size_t ko = (size_t)ti * 32;
    short* a0 = &As[st][w * 1024];
    glds16(ag0 + ko, a0); glds16(ag1 + ko, a0 + 512);
    short* b0 = &Bs[st][w * 1024];
    glds16(bg0 + ko, b0); glds16(bg1 + ko, b0 + 512);
  };
  issue(0, 0); issue(1, 1); issue(2, 2);   // 12 outstanding per wave

  int p = 0;
  for (int i = 0; i < NI; i++) {
    // wait: oldest 4 glds (tile i) landed; 8 younger stay in flight across barrier
    asm volatile("s_waitcnt vmcnt(8)\n\ts_barrier" ::: "memory");
    const short* afb = &As[p][wr * 2048 + fo];
    const short* bfb = &Bs[p][wc * 2048 + fo];
    bf16x8 af[4], bfr[4];
#pragma unroll
    for (int rt = 0; rt < 4; rt++) af[rt] = *(const bf16x8*)(afb + rt * 512);
#pragma unroll
    for (int ct = 0; ct < 4; ct++) bfr[ct] = *(const bf16x8*)(bfb + ct * 512);
#pragma unroll
    for (int rt = 0; rt < 4; rt++)
#pragma unroll
      for (int ct = 0; ct < 4; ct++)
        acc[rt][ct] = __builtin_amdgcn_mfma_f32_16x16x32_bf16(af[rt], bfr[ct], acc[rt][ct], 0, 0, 0);
    // all waves done reading stage p (ds_reads complete) -> safe to overwrite
    asm volatile("s_waitcnt lgkmcnt(0)\n\ts_barrier" ::: "memory");
    int nt = i + 3;
    if (nt >= NI) nt -= NI;         // tail: dummy wrap keeps vmcnt accounting uniform;
    issue(nt, p);                   // lands in a stage never read again
    p = (p == 2) ? 0 : p + 1;
  }

  // epilogue: C/D map col=lane&15, row=(lane>>4)*4+reg  [m89/m91-verified]
  const float* bb = bias;
  void* op = outp;
  int nofs = 0, Nout = N;
  bool sig = false;
  if (MODE == 4) {
    Nout = N >> 1;
    if (n0 >= Nout) { bb = bias2; op = outp2; nofs = Nout; sig = true; }
  }
  const int gmb = m0 + wr * 64 + qd * 4;
  const int gnb = n0 + wc * 64 + l16;
#pragma unroll
  for (int ct = 0; ct < 4; ct++) {
    int gn = gnb + ct * 16;
    float bc = bb[gn - nofs];
#pragma unroll
    for (int rt = 0; rt < 4; rt++) {
#pragma unroll
      for (int r = 0; r < 4; r++) {
        int gm = gmb + rt * 16 + r;
        float vv = acc[rt][ct][r] + bc;
        if (MODE == 2) vv = vv * fsigmoid(vv);
        if (MODE == 4 && sig) vv = fsigmoid(vv);
        size_t oidx = (size_t)gm * Nout + (gn - nofs);
        if (MODE == 3) vv += res[oidx];
        if (OUTBF16) ((bf16*)op)[oidx] = __float2bfloat16(vv);
        else         ((float*)op)[oidx] = vv;
      }
    }
  }
}

// ---------------- chunked linear-recurrence scan (u bf16, 4 ch/thread) ----------------
__global__ void k_scan_a(const bf16* __restrict__ u, const float* __restrict__ dl,
                         float* __restrict__ clast) {
  int t = threadIdx.x;            // 0..191, 4 channels each
  int g = blockIdx.x;
  int d0 = t * 4;
  float dec[4], s[4] = {0.f, 0.f, 0.f, 0.f};
#pragma unroll
  for (int c = 0; c < 4; c++) dec[c] = fsigmoid(dl[d0 + c]);
  const ushort4* up = (const ushort4*)(u + (size_t)g * S_T * D_MOD) + t;
  for (int tt = 0; tt < S_T; tt++) {
    ushort4 uv = up[(size_t)tt * 192];
    s[0] = fmaf(dec[0], s[0], bf2f(uv.x));
    s[1] = fmaf(dec[1], s[1], bf2f(uv.y));
    s[2] = fmaf(dec[2], s[2], bf2f(uv.z));
    s[3] = fmaf(dec[3], s[3], bf2f(uv.w));
  }
#pragma unroll
  for (int c = 0; c < 4; c++) clast[(size_t)g * D_MOD + d0 + c] = s[c];
}

__global__ void k_scan_b(const float* __restrict__ clast, const float* __restrict__ dl,
                         float* __restrict__ carry) {
  int d = threadIdx.x;
  float decay = fsigmoid(dl[d]);
  float aT = decay;
#pragma unroll
  for (int i = 0; i < 6; i++) aT *= aT;   // decay^64
  float c = 0.f;
  for (int g = 0; g < S_G; g++) {
    carry[(size_t)g * D_MOD + d] = c;
    c = fmaf(aT, c, clast[(size_t)g * D_MOD + d]);
  }
}

__global__ void k_scan_c(const bf16* __restrict__ u, const float* __restrict__ dl,
                         const float* __restrict__ carry, bf16* __restrict__ gate_s) {
  int t = threadIdx.x;            // 0..191
  int g = blockIdx.x;
  int d0 = t * 4;
  float dec[4], s[4];
#pragma unroll
  for (int c = 0; c < 4; c++) {
    dec[c] = fsigmoid(dl[d0 + c]);
    s[c] = carry[(size_t)g * D_MOD + d0 + c];
  }
  const ushort4* up = (const ushort4*)(u + (size_t)g * S_T * D_MOD) + t;
  ushort4* gp = (ushort4*)(gate_s + (size_t)g * S_T * D_MOD) + t;
  for (int tt = 0; tt < S_T; tt++) {
    ushort4 uv = up[(size_t)tt * 192];
    ushort4 gv = gp[(size_t)tt * 192];
    s[0] = fmaf(dec[0], s[0], bf2f(uv.x));
    s[1] = fmaf(dec[1], s[1], bf2f(uv.y));
    s[2] = fmaf(dec[2], s[2], bf2f(uv.z));
    s[3] = fmaf(dec[3], s[3], bf2f(uv.w));
    ushort4 ov;
    ov.x = f2bf(s[0] * bf2f(gv.x));
    ov.y = f2bf(s[1] * bf2f(gv.y));
    ov.z = f2bf(s[2] * bf2f(gv.z));
    ov.w = f2bf(s[3] * bf2f(gv.w));
    gp[(size_t)tt * 192] = ov;
  }
}

extern "C" void kernel_launch(void* const* d_in, const int* in_sizes, int n_in,
                              void* d_out, int out_size, void* d_ws, size_t ws_size,
                              hipStream_t stream) {
  const float* nf     = (const float*)d_in[0];
  const float* W_proj = (const float*)d_in[1];
  const float* b_proj = (const float*)d_in[2];
  const float* ln_s_g = (const float*)d_in[3];
  const float* ln_s_b = (const float*)d_in[4];
  const float* W_in   = (const float*)d_in[5];
  const float* b_in   = (const float*)d_in[6];
  const float* W_gate = (const float*)d_in[7];
  const float* b_gate = (const float*)d_in[8];
  const float* W_out  = (const float*)d_in[9];
  const float* b_out  = (const float*)d_in[10];
  const float* dlogit = (const float*)d_in[11];
  const float* ln_f_g = (const float*)d_in[12];
  const float* ln_f_b = (const float*)d_in[13];
  const float* W_ff1  = (const float*)d_in[14];
  const float* b_ff1  = (const float*)d_in[15];
  const float* W_ff2  = (const float*)d_in[16];
  const float* b_ff2  = (const float*)d_in[17];
  const float* ln_o_g = (const float*)d_in[18];
  const float* ln_o_b = (const float*)d_in[19];
  (void)in_sizes; (void)n_in;

  char* ws = (char*)d_ws;
  size_t off = 0;
  auto alloc = [&](size_t bytes) -> char* {
    char* p = ws + off;
    off = (off + bytes + 255) & ~(size_t)255;
    return p;
  };
  // big path (~194 MB): all-layer transposed weights staged once; else per-layer (~136 MB)
  const bool big = ws_size >= (195ull << 20);
  const size_t wmul = big ? N_LAYER : 1;

  float* x     = (float*)alloc(sizeof(float) * (size_t)L_TOK * D_MOD);   // 50.3 MB
  bf16*  h     = (bf16*)alloc(2ull * L_TOK * D_MOD);                     // 25.2 MB
  // shared region (50.3 MB): nfb (pre-loop) | u+gate (recurrence) | tb (FF)
  char*  ug    = alloc(2ull * L_TOK * D_FF);
  bf16*  u     = (bf16*)ug;
  bf16*  gate  = (bf16*)(ug + 2ull * L_TOK * D_MOD);
  bf16*  tb    = (bf16*)ug;
  bf16*  nfb   = (bf16*)ug;
  bf16*  WprojT= (bf16*)alloc(2ull * D_INP * D_MOD);
  bf16*  WigT  = (bf16*)alloc(2ull * wmul * (2 * D_MOD) * D_MOD);  // [W_in^T ; W_gate^T]
  bf16*  WoT   = (bf16*)alloc(2ull * wmul * D_MOD * D_MOD);
  bf16*  Wff1T = (bf16*)alloc(2ull * wmul * D_MOD * D_FF);
  bf16*  Wff2T = (bf16*)alloc(2ull * wmul * D_FF * D_MOD);
  float* clast = (float*)alloc(sizeof(float) * (size_t)S_G * D_MOD);
  float* carry = (float*)alloc(sizeof(float) * (size_t)S_G * D_MOD);

  const size_t DD = (size_t)D_MOD * D_MOD, DF = (size_t)D_MOD * D_FF;
  dim3 tb32(32, 8);
  k_f32_to_bf16v<<<(L_TOK * D_INP / 4 + 255) / 256, 256, 0, stream>>>(
      (const float4*)nf, (ushort4*)nfb, L_TOK * D_INP / 4);
  k_transpose_bf16<<<dim3(D_MOD / 32, D_INP / 32, 1), tb32, 0, stream>>>(
      W_proj, WprojT, D_INP, D_MOD, 0, 0);
  if (big) {
    k_transpose_bf16<<<dim3(D_MOD / 32, D_MOD / 32, N_LAYER), tb32, 0, stream>>>(
        W_in,   WigT,       D_MOD, D_MOD, DD, 2 * DD);
    k_transpose_bf16<<<dim3(D_MOD / 32, D_MOD / 32, N_LAYER), tb32, 0, stream>>>(
        W_gate, WigT + DD,  D_MOD, D_MOD, DD, 2 * DD);
    k_transpose_bf16<<<dim3(D_MOD / 32, D_MOD / 32, N_LAYER), tb32, 0, stream>>>(
        W_out,  WoT,        D_MOD, D_MOD, DD, DD);
    k_transpose_bf16<<<dim3(D_FF / 32,  D_MOD / 32, N_LAYER), tb32, 0, stream>>>(
        W_ff1,  Wff1T,      D_MOD, D_FF,  DF, DF);
    k_transpose_bf16<<<dim3(D_MOD / 32, D_FF / 32,  N_LAYER), tb32, 0, stream>>>(
        W_ff2,  Wff2T,      D_FF,  D_MOD, DF, DF);
  }

  // x = nf @ W_proj + b_proj (f32)
  k_gemm128<0, false><<<128 * 6, 256, 0, stream>>>(
      (const short*)nfb, (const short*)WprojT, b_proj, nullptr, nullptr, x, nullptr,
      D_MOD, D_INP, 6);

  for (int l = 0; l < N_LAYER; l++) {
    const bf16 *wigT, *woT, *wf1T, *wf2T;
    if (big) {
      wigT = WigT  + (size_t)l * 2 * DD;
      woT  = WoT   + (size_t)l * DD;
      wf1T = Wff1T + (size_t)l * DF;
      wf2T = Wff2T + (size_t)l * DF;
    } else {
      k_transpose_bf16<<<dim3(D_MOD / 32, D_MOD / 32, 1), tb32, 0, stream>>>(
          W_in + (size_t)l * DD, WigT, D_MOD, D_MOD, 0, 0);
      k_transpose_bf16<<<dim3(D_MOD / 32, D_MOD / 32, 1), tb32, 0, stream>>>(
          W_gate + (size_t)l * DD, WigT + DD, D_MOD, D_MOD, 0, 0);
      k_transpose_bf16<<<dim3(D_MOD / 32, D_MOD / 32, 1), tb32, 0, stream>>>(
          W_out + (size_t)l * DD, WoT, D_MOD, D_MOD, 0, 0);
      k_transpose_bf16<<<dim3(D_FF / 32, D_MOD / 32, 1), tb32, 0, stream>>>(
          W_ff1 + (size_t)l * DF, Wff1T, D_MOD, D_FF, 0, 0);
      k_transpose_bf16<<<dim3(D_MOD / 32, D_FF / 32, 1), tb32, 0, stream>>>(
          W_ff2 + (size_t)l * DF, Wff2T, D_FF, D_MOD, 0, 0);
      wigT = WigT; woT = WoT; wf1T = Wff1T; wf2T = Wff2T;
    }

    // h = LN_s(x) -> bf16
    k_layernorm<true><<<L_TOK / 4, 256, 0, stream>>>(x, ln_s_g + l * D_MOD, ln_s_b + l * D_MOD, h);
    // fused: u = h@W_in + b_in ; gate = sigmoid(h@W_gate + b_gate)   (both bf16)
    k_gemm128<4, true><<<128 * 12, 256, 0, stream>>>(
        (const short*)h, (const short*)wigT, b_in + l * D_MOD, b_gate + l * D_MOD,
        nullptr, u, gate, 2 * D_MOD, D_MOD, 12);
    // chunked scan; s = states*gate -> gate buffer (bf16)
    k_scan_a<<<S_G, 192, 0, stream>>>(u, dlogit + l * D_MOD, clast);
    k_scan_b<<<1, D_MOD, 0, stream>>>(clast, dlogit + l * D_MOD, carry);
    k_scan_c<<<S_G, 192, 0, stream>>>(u, dlogit + l * D_MOD, carry, gate);
    // x = x + s @ W_out + b_out (f32)
    k_gemm128<3, false><<<128 * 6, 256, 0, stream>>>(
        (const short*)gate, (const short*)woT, b_out + l * D_MOD, nullptr, x, x, nullptr,
        D_MOD, D_MOD, 6);
    // hf = LN_f(x) -> bf16 (reuse h)
    k_layernorm<true><<<L_TOK / 4, 256, 0, stream>>>(x, ln_f_g + l * D_MOD, ln_f_b + l * D_MOD, h);
    // tb = silu(hf @ W_ff1 + b_ff1) (bf16)
    k_gemm128<2, true><<<128 * 12, 256, 0, stream>>>(
        (const short*)h, (const short*)wf1T, b_ff1 + l * D_FF, nullptr, nullptr, tb, nullptr,
        D_FF, D_MOD, 12);
    // x = x + tb @ W_ff2 + b_ff2 (f32)
    k_gemm128<3, false><<<128 * 6, 256, 0, stream>>>(
        (const short*)tb, (const short*)wf2T, b_ff2 + l * D_MOD, nullptr, x, x, nullptr,
        D_MOD, D_FF, 6);
  }

  // out = LN_o(x) (f32)
  k_layernorm<false><<<L_TOK / 4, 256, 0, stream>>>(x, ln_o_g, ln_o_b, d_out);
}

// Round 6
// 2277.289 us; speedup vs baseline: 1.1900x; 1.1900x over previous
//
#include <hip/hip_runtime.h>
#include <hip/hip_bf16.h>
#include <math.h>
#include <string.h>

#define L_TOK 16384
#define D_INP 256
#define D_MOD 768
#define D_FF  1536
#define N_LAYER 8
#define S_T 64
#define S_G 256
#define EPSV 1e-5f

typedef short bf16x8 __attribute__((ext_vector_type(8)));
typedef float f32x4 __attribute__((ext_vector_type(4)));
typedef __hip_bfloat16 bf16;
typedef unsigned int u32;
typedef unsigned short u16;

__device__ __forceinline__ float fsigmoid(float z) { return 1.0f / (1.0f + __expf(-z)); }

__device__ __forceinline__ u16 f2bf(float f) {
  __hip_bfloat16 h = __float2bfloat16(f);
  u16 r; memcpy(&r, &h, 2); return r;
}
__device__ __forceinline__ float bf2f(u16 v) {
  u32 x = ((u32)v) << 16; float f; memcpy(&f, &x, 4); return f;
}

// async global->LDS, 16B per lane. LDS dest = (wave-uniform base) + lane*16.
__device__ __forceinline__ void glds16(const short* g, short* l) {
  __builtin_amdgcn_global_load_lds(
      (const __attribute__((address_space(1))) unsigned int*)(g),
      (__attribute__((address_space(3))) unsigned int*)(l), 16, 0, 0);
}

// ---------------- f32 -> bf16, vectorized ----------------
__global__ void k_f32_to_bf16v(const float4* __restrict__ src, ushort4* __restrict__ dst, int n4) {
  int i = blockIdx.x * blockDim.x + threadIdx.x;
  if (i < n4) {
    float4 v = src[i];
    ushort4 o; o.x = f2bf(v.x); o.y = f2bf(v.y); o.z = f2bf(v.z); o.w = f2bf(v.w);
    dst[i] = o;
  }
}

// ------- transpose+convert (+optional LN-fold): src [z][R,C] f32 -> dst [z][C,R] bf16
// FOLD: dst[n,k] = g[k]*W[k,n]; atomically accumulate wacc[n] += sum_k g[k]W[k,n],
//       bacc[n] += sum_k bln[k]W[k,n]  (wacc/bacc pre-zeroed).
// R, C multiples of 32. block (32,8), grid (C/32, R/32, NZ)
template<bool FOLD>
__global__ void k_transpose_fold(const float* __restrict__ src, bf16* __restrict__ dst,
                                 int R, int C, size_t sstride, size_t dstride,
                                 const float* __restrict__ gv, const float* __restrict__ bv,
                                 float* __restrict__ wacc, float* __restrict__ bacc,
                                 int vstride) {
  __shared__ float tile[32][33];
  int z = blockIdx.z;
  const float* s = src + (size_t)z * sstride;
  bf16* d = dst + (size_t)z * dstride;
  int r0 = blockIdx.y * 32, c0 = blockIdx.x * 32;
  int tx = threadIdx.x, ty = threadIdx.y;
#pragma unroll
  for (int i = ty; i < 32; i += 8)
    tile[i][tx] = s[(size_t)(r0 + i) * C + (c0 + tx)];
  __syncthreads();
  float gk = 1.0f;
  if (FOLD) gk = gv[(size_t)z * R + r0 + tx];
#pragma unroll
  for (int i = ty; i < 32; i += 8) {
    float val = tile[tx][i];
    if (FOLD) val *= gk;
    d[(size_t)(c0 + i) * R + (r0 + tx)] = __float2bfloat16(val);
  }
  if (FOLD && ty == 0) {
    const float* gz = gv + (size_t)z * R + r0;
    const float* bz = bv + (size_t)z * R + r0;
    float s1 = 0.f, s2 = 0.f;
#pragma unroll 8
    for (int j = 0; j < 32; j++) {
      float wv = tile[j][tx];
      s1 += gz[j] * wv;
      s2 += bz[j] * wv;
    }
    atomicAdd(&wacc[(size_t)z * vstride + c0 + tx], s1);
    atomicAdd(&bacc[(size_t)z * vstride + c0 + tx], s2);
  }
}

// ---------------- bf16 MFMA GEMM (round-4 pipeline) + LN-fold / stats epilogues -----
// C[16384,N] = A[16384,K] * Bt[N,K]^T. 128x128 tile, BK=32, 256 thr (2x2 waves),
// glds w=16, 2-stage LDS dbuf, one __syncthreads per iter, XOR LDS swizzle,
// XCD band swizzle. Output always bf16 except nothing (all bf16 now).
// MODE: 0 bias; 2 silu; 3 bias+residual(bf16,in-place); 4 split u|gate.
// LNFOLD: A is the raw residual x; apply val = rv*acc - rv*mu*wvec[gn] + bvec[gn] + bias.
// STATS: accumulate per-row sum/sumsq of written bf16 values into stats_out (pre-zeroed).
template<int MODE, bool LNFOLD, bool STATS>
__global__ __launch_bounds__(256, 4) void k_gemm128(
    const short* __restrict__ A, const short* __restrict__ Bt,
    const float* __restrict__ bias, const float* __restrict__ bias2,
    const float* __restrict__ wvec, const float* __restrict__ bvec,
    const float* __restrict__ stats_in, float* __restrict__ stats_out,
    u16* __restrict__ res, u16* __restrict__ outp, u16* __restrict__ outp2,
    int N, int K, int ncol)
{
  __shared__ short As[2][128 * 32];
  __shared__ short Bs[2][128 * 32];
  __shared__ float s_mu[128], s_rv[128];
  const int tid = threadIdx.x;
  const int lane = tid & 63, w = tid >> 6;
  const int wr = w >> 1, wc = w & 1;
  const int l16 = lane & 15, qd = lane >> 4;

  const int b = blockIdx.x;
  const int xcd = b & 7, t = b >> 3;
  const int m0 = (xcd * 16 + t / ncol) * 128;
  const int n0 = (t % ncol) * 128;

  const int sr = lane >> 2, sc = lane & 3;
  const int ar = w * 32 + sr;
  const int acx = sc ^ ((ar >> 1) & 3);
  const short* ag0 = A  + (size_t)(m0 + ar) * K + acx * 8;
  const short* ag1 = ag0 + (size_t)16 * K;
  const short* bg0 = Bt + (size_t)(n0 + ar) * K + acx * 8;
  const short* bg1 = bg0 + (size_t)16 * K;

  const int fo = (qd ^ ((l16 >> 1) & 3)) * 8 + l16 * 32;

  f32x4 acc[4][4];
#pragma unroll
  for (int i = 0; i < 4; i++)
#pragma unroll
    for (int j = 0; j < 4; j++) acc[i][j] = (f32x4){0.f, 0.f, 0.f, 0.f};

  // preload tile 0 -> buffer 0 (full exec mask: glds must be issued by all lanes)
  {
    short* a0 = &As[0][w * 1024];
    glds16(ag0, a0); glds16(ag1, a0 + 512);
    short* b0 = &Bs[0][w * 1024];
    glds16(bg0, b0); glds16(bg1, b0 + 512);
  }
  if (LNFOLD && tid < 128) {       // row stats -> per-row mu, rv in LDS
    float sv  = stats_in[2 * (m0 + tid)];
    float sq  = stats_in[2 * (m0 + tid) + 1];
    float mu  = sv * (1.0f / (float)D_MOD);
    float var = sq * (1.0f / (float)D_MOD) - mu * mu;
    s_mu[tid] = mu;
    s_rv[tid] = 1.0f / sqrtf(var + EPSV);
  }
  int p = 0;
  for (int k0 = 0; k0 < K; k0 += 32, p ^= 1) {
    __syncthreads();
    if (k0 + 32 < K) {
      short* a0 = &As[p ^ 1][w * 1024];
      glds16(ag0 + k0 + 32, a0); glds16(ag1 + k0 + 32, a0 + 512);
      short* b0 = &Bs[p ^ 1][w * 1024];
      glds16(bg0 + k0 + 32, b0); glds16(bg1 + k0 + 32, b0 + 512);
    }
    const short* afb = &As[p][wr * 2048 + fo];
    const short* bfb = &Bs[p][wc * 2048 + fo];
    bf16x8 af[4], bfr[4];
#pragma unroll
    for (int rt = 0; rt < 4; rt++) af[rt] = *(const bf16x8*)(afb + rt * 512);
#pragma unroll
    for (int ct = 0; ct < 4; ct++) bfr[ct] = *(const bf16x8*)(bfb + ct * 512);
#pragma unroll
    for (int rt = 0; rt < 4; rt++)
#pragma unroll
      for (int ct = 0; ct < 4; ct++)
        acc[rt][ct] = __builtin_amdgcn_mfma_f32_16x16x32_bf16(af[rt], bfr[ct], acc[rt][ct], 0, 0, 0);
  }

  // ---- epilogue. C/D map col=lane&15, row=(lane>>4)*4+reg ----
  const float* bb = bias;
  u16* op = outp;
  int nofs = 0, Nout = N;
  bool sig = false;
  if (MODE == 4) {
    Nout = N >> 1;
    if (n0 >= Nout) { bb = bias2; op = outp2; nofs = Nout; sig = true; }
  }
  const int gmb = m0 + wr * 64 + qd * 4;
  const int gnb = n0 + wc * 64 + l16;
  float bc[4], wv4[4], bv4[4];
#pragma unroll
  for (int ct = 0; ct < 4; ct++) {
    int gn = gnb + ct * 16;
    bc[ct] = bb[gn - nofs];
    if (LNFOLD) { wv4[ct] = wvec[gn]; bv4[ct] = bvec[gn]; }
  }
#pragma unroll
  for (int rt = 0; rt < 4; rt++) {
#pragma unroll
    for (int r = 0; r < 4; r++) {
      const int gm = gmb + rt * 16 + r;
      float mu = 0.f, rv = 0.f;
      if (LNFOLD) { mu = s_mu[gm - m0]; rv = s_rv[gm - m0]; }
      float ps = 0.f, ps2 = 0.f;
#pragma unroll
      for (int ct = 0; ct < 4; ct++) {
        int gn = gnb + ct * 16;
        float vv = acc[rt][ct][r];
        if (LNFOLD) vv = rv * vv - rv * mu * wv4[ct] + bv4[ct] + bc[ct];
        else        vv += bc[ct];
        if (MODE == 2) vv = vv * fsigmoid(vv);
        if (MODE == 4 && sig) vv = fsigmoid(vv);
        size_t oidx = (size_t)gm * Nout + (gn - nofs);
        if (MODE == 3) vv += bf2f(res[oidx]);
        u16 rb = f2bf(vv);
        op[oidx] = rb;
        if (STATS) { float fv = bf2f(rb); ps += fv; ps2 += fv * fv; }
      }
      if (STATS) {
        // reduce across the 16 lanes (same qd group) that share this row
#pragma unroll
        for (int o = 1; o < 16; o <<= 1) {
          ps  += __shfl_xor(ps, o, 64);
          ps2 += __shfl_xor(ps2, o, 64);
        }
        if (l16 == 0) {
          atomicAdd(&stats_out[2 * gm], ps);
          atomicAdd(&stats_out[2 * gm + 1], ps2);
        }
      }
    }
  }
}

// ---------------- chunked linear-recurrence scan (u bf16, 4 ch/thread) ----------------
__global__ void k_scan_a(const bf16* __restrict__ u, const float* __restrict__ dl,
                         float* __restrict__ clast) {
  int t = threadIdx.x;            // 0..191
  int g = blockIdx.x;
  int d0 = t * 4;
  float dec[4], s[4] = {0.f, 0.f, 0.f, 0.f};
#pragma unroll
  for (int c = 0; c < 4; c++) dec[c] = fsigmoid(dl[d0 + c]);
  const ushort4* up = (const ushort4*)(u + (size_t)g * S_T * D_MOD) + t;
  for (int tt = 0; tt < S_T; tt++) {
    ushort4 uv = up[(size_t)tt * 192];
    s[0] = fmaf(dec[0], s[0], bf2f(uv.x));
    s[1] = fmaf(dec[1], s[1], bf2f(uv.y));
    s[2] = fmaf(dec[2], s[2], bf2f(uv.z));
    s[3] = fmaf(dec[3], s[3], bf2f(uv.w));
  }
#pragma unroll
  for (int c = 0; c < 4; c++) clast[(size_t)g * D_MOD + d0 + c] = s[c];
}

__global__ void k_scan_b(const float* __restrict__ clast, const float* __restrict__ dl,
                         float* __restrict__ carry) {
  int d = threadIdx.x;
  float decay = fsigmoid(dl[d]);
  float aT = decay;
#pragma unroll
  for (int i = 0; i < 6; i++) aT *= aT;   // decay^64
  float c = 0.f;
  for (int g = 0; g < S_G; g++) {
    carry[(size_t)g * D_MOD + d] = c;
    c = fmaf(aT, c, clast[(size_t)g * D_MOD + d]);
  }
}

__global__ void k_scan_c(const bf16* __restrict__ u, const float* __restrict__ dl,
                         const float* __restrict__ carry, bf16* __restrict__ gate_s) {
  int t = threadIdx.x;            // 0..191
  int g = blockIdx.x;
  int d0 = t * 4;
  float dec[4], s[4];
#pragma unroll
  for (int c = 0; c < 4; c++) {
    dec[c] = fsigmoid(dl[d0 + c]);
    s[c] = carry[(size_t)g * D_MOD + d0 + c];
  }
  const ushort4* up = (const ushort4*)(u + (size_t)g * S_T * D_MOD) + t;
  ushort4* gp = (ushort4*)(gate_s + (size_t)g * S_T * D_MOD) + t;
  for (int tt = 0; tt < S_T; tt++) {
    ushort4 uv = up[(size_t)tt * 192];
    ushort4 gv = gp[(size_t)tt * 192];
    s[0] = fmaf(dec[0], s[0], bf2f(uv.x));
    s[1] = fmaf(dec[1], s[1], bf2f(uv.y));
    s[2] = fmaf(dec[2], s[2], bf2f(uv.z));
    s[3] = fmaf(dec[3], s[3], bf2f(uv.w));
    ushort4 ov;
    ov.x = f2bf(s[0] * bf2f(gv.x));
    ov.y = f2bf(s[1] * bf2f(gv.y));
    ov.z = f2bf(s[2] * bf2f(gv.z));
    ov.w = f2bf(s[3] * bf2f(gv.w));
    gp[(size_t)tt * 192] = ov;
  }
}

// ---------------- final LN: x bf16 + precomputed stats -> f32 out ----------------
__global__ __launch_bounds__(256) void k_ln_final(const u16* __restrict__ x,
    const float* __restrict__ stats, const float* __restrict__ g,
    const float* __restrict__ b, float* __restrict__ outp) {
  int wv = threadIdx.x >> 6, lane = threadIdx.x & 63;
  int row = blockIdx.x * 4 + wv;
  float sv = stats[2 * row], sq = stats[2 * row + 1];
  float mu = sv * (1.0f / (float)D_MOD);
  float var = sq * (1.0f / (float)D_MOD) - mu * mu;
  float rv = 1.0f / sqrtf(var + EPSV);
  const ushort4* xr = (const ushort4*)(x + (size_t)row * D_MOD);
  const float4* g4 = (const float4*)g;
  const float4* b4 = (const float4*)b;
  float4* o4 = (float4*)(outp + (size_t)row * D_MOD);
#pragma unroll
  for (int j = 0; j < 3; j++) {
    int f = j * 64 + lane;
    ushort4 xv = xr[f];
    float4 gg = g4[f], bb = b4[f], ov;
    ov.x = (bf2f(xv.x) - mu) * rv * gg.x + bb.x;
    ov.y = (bf2f(xv.y) - mu) * rv * gg.y + bb.y;
    ov.z = (bf2f(xv.z) - mu) * rv * gg.z + bb.z;
    ov.w = (bf2f(xv.w) - mu) * rv * gg.w + bb.w;
    o4[f] = ov;
  }
}

extern "C" void kernel_launch(void* const* d_in, const int* in_sizes, int n_in,
                              void* d_out, int out_size, void* d_ws, size_t ws_size,
                              hipStream_t stream) {
  const float* nf     = (const float*)d_in[0];
  const float* W_proj = (const float*)d_in[1];
  const float* b_proj = (const float*)d_in[2];
  const float* ln_s_g = (const float*)d_in[3];
  const float* ln_s_b = (const float*)d_in[4];
  const float* W_in   = (const float*)d_in[5];
  const float* b_in   = (const float*)d_in[6];
  const float* W_gate = (const float*)d_in[7];
  const float* b_gate = (const float*)d_in[8];
  const float* W_out  = (const float*)d_in[9];
  const float* b_out  = (const float*)d_in[10];
  const float* dlogit = (const float*)d_in[11];
  const float* ln_f_g = (const float*)d_in[12];
  const float* ln_f_b = (const float*)d_in[13];
  const float* W_ff1  = (const float*)d_in[14];
  const float* b_ff1  = (const float*)d_in[15];
  const float* W_ff2  = (const float*)d_in[16];
  const float* b_ff2  = (const float*)d_in[17];
  const float* ln_o_g = (const float*)d_in[18];
  const float* ln_o_b = (const float*)d_in[19];
  (void)in_sizes; (void)n_in;

  char* ws = (char*)d_ws;
  size_t off = 0;
  auto alloc = [&](size_t bytes) -> char* {
    char* p = ws + off;
    off = (off + bytes + 255) & ~(size_t)255;
    return p;
  };
  const bool big = ws_size >= (160ull << 20);
  const size_t wmul = big ? N_LAYER : 1;

  u16*   x     = (u16*)alloc(2ull * L_TOK * D_MOD);        // residual stream, bf16 (25 MB)
  // shared region (50.3 MB): nfb (pre-loop) | u+gate (recurrence) | tb (FF)
  char*  ug    = alloc(2ull * L_TOK * D_FF);
  u16*   u     = (u16*)ug;
  u16*   gate  = (u16*)(ug + 2ull * L_TOK * D_MOD);
  u16*   tb    = (u16*)ug;
  u16*   nfb   = (u16*)ug;
  bf16*  WprojT= (bf16*)alloc(2ull * D_INP * D_MOD);
  bf16*  WigT  = (bf16*)alloc(2ull * wmul * (2 * D_MOD) * D_MOD);  // [g∘W_in^T ; g∘W_gate^T]
  bf16*  WoT   = (bf16*)alloc(2ull * wmul * D_MOD * D_MOD);
  bf16*  Wff1T = (bf16*)alloc(2ull * wmul * D_MOD * D_FF);
  bf16*  Wff2T = (bf16*)alloc(2ull * wmul * D_FF * D_MOD);
  float* clast = (float*)alloc(sizeof(float) * (size_t)S_G * D_MOD);
  float* carry = (float*)alloc(sizeof(float) * (size_t)S_G * D_MOD);
  // zeroed region: stats slots [17][16384][2] + fold vectors
  char*  zbase = alloc(0);
  float* stats = (float*)alloc(sizeof(float) * 17ull * L_TOK * 2);     // 2.23 MB
  float* wvig  = (float*)alloc(sizeof(float) * N_LAYER * 2 * D_MOD);   // g_s@[W_in|W_gate]
  float* bvig  = (float*)alloc(sizeof(float) * N_LAYER * 2 * D_MOD);
  float* wvf1  = (float*)alloc(sizeof(float) * N_LAYER * D_FF);        // g_f@W_ff1
  float* bvf1  = (float*)alloc(sizeof(float) * N_LAYER * D_FF);
  size_t zbytes = (size_t)((char*)ws + off - zbase);
  hipMemsetAsync(zbase, 0, zbytes, stream);

  const size_t DD = (size_t)D_MOD * D_MOD, DF = (size_t)D_MOD * D_FF;
  auto statslot = [&](int s) { return stats + (size_t)s * L_TOK * 2; };
  dim3 tb32(32, 8);
  k_f32_to_bf16v<<<(L_TOK * D_INP / 4 + 255) / 256, 256, 0, stream>>>(
      (const float4*)nf, (ushort4*)nfb, L_TOK * D_INP / 4);
  k_transpose_fold<false><<<dim3(D_MOD / 32, D_INP / 32, 1), tb32, 0, stream>>>(
      W_proj, WprojT, D_INP, D_MOD, 0, 0, nullptr, nullptr, nullptr, nullptr, 0);
  if (big) {
    k_transpose_fold<true><<<dim3(D_MOD / 32, D_MOD / 32, N_LAYER), tb32, 0, stream>>>(
        W_in,   WigT,      D_MOD, D_MOD, DD, 2 * DD, ln_s_g, ln_s_b, wvig,       bvig,       2 * D_MOD);
    k_transpose_fold<true><<<dim3(D_MOD / 32, D_MOD / 32, N_LAYER), tb32, 0, stream>>>(
        W_gate, WigT + DD, D_MOD, D_MOD, DD, 2 * DD, ln_s_g, ln_s_b, wvig + D_MOD, bvig + D_MOD, 2 * D_MOD);
    k_transpose_fold<false><<<dim3(D_MOD / 32, D_MOD / 32, N_LAYER), tb32, 0, stream>>>(
        W_out,  WoT,       D_MOD, D_MOD, DD, DD, nullptr, nullptr, nullptr, nullptr, 0);
    k_transpose_fold<true><<<dim3(D_FF / 32,  D_MOD / 32, N_LAYER), tb32, 0, stream>>>(
        W_ff1,  Wff1T,     D_MOD, D_FF,  DF, DF, ln_f_g, ln_f_b, wvf1, bvf1, D_FF);
    k_transpose_fold<false><<<dim3(D_MOD / 32, D_FF / 32,  N_LAYER), tb32, 0, stream>>>(
        W_ff2,  Wff2T,     D_FF,  D_MOD, DF, DF, nullptr, nullptr, nullptr, nullptr, 0);
  }

  // x = nf @ W_proj + b_proj  (bf16 out + stats slot 0)
  k_gemm128<0, false, true><<<128 * 6, 256, 0, stream>>>(
      (const short*)nfb, (const short*)WprojT, b_proj, nullptr, nullptr, nullptr,
      nullptr, statslot(0), nullptr, x, nullptr, D_MOD, D_INP, 6);

  for (int l = 0; l < N_LAYER; l++) {
    const bf16 *wigT, *woT, *wf1T, *wf2T;
    if (big) {
      wigT = WigT  + (size_t)l * 2 * DD;
      woT  = WoT   + (size_t)l * DD;
      wf1T = Wff1T + (size_t)l * DF;
      wf2T = Wff2T + (size_t)l * DF;
    } else {
      k_transpose_fold<true><<<dim3(D_MOD / 32, D_MOD / 32, 1), tb32, 0, stream>>>(
          W_in + (size_t)l * DD, WigT, D_MOD, D_MOD, 0, 0,
          ln_s_g + l * D_MOD, ln_s_b + l * D_MOD, wvig + (size_t)l * 2 * D_MOD, bvig + (size_t)l * 2 * D_MOD, 0);
      k_transpose_fold<true><<<dim3(D_MOD / 32, D_MOD / 32, 1), tb32, 0, stream>>>(
          W_gate + (size_t)l * DD, WigT + DD, D_MOD, D_MOD, 0, 0,
          ln_s_g + l * D_MOD, ln_s_b + l * D_MOD, wvig + (size_t)l * 2 * D_MOD + D_MOD, bvig + (size_t)l * 2 * D_MOD + D_MOD, 0);
      k_transpose_fold<false><<<dim3(D_MOD / 32, D_MOD / 32, 1), tb32, 0, stream>>>(
          W_out + (size_t)l * DD, WoT, D_MOD, D_MOD, 0, 0, nullptr, nullptr, nullptr, nullptr, 0);
      k_transpose_fold<true><<<dim3(D_FF / 32, D_MOD / 32, 1), tb32, 0, stream>>>(
          W_ff1 + (size_t)l * DF, Wff1T, D_MOD, D_FF, 0, 0,
          ln_f_g + l * D_MOD, ln_f_b + l * D_MOD, wvf1 + (size_t)l * D_FF, bvf1 + (size_t)l * D_FF, 0);
      k_transpose_fold<false><<<dim3(D_MOD / 32, D_FF / 32, 1), tb32, 0, stream>>>(
          W_ff2 + (size_t)l * DF, Wff2T, D_FF, D_MOD, 0, 0, nullptr, nullptr, nullptr, nullptr, 0);
      wigT = WigT; woT = WoT; wf1T = Wff1T; wf2T = Wff2T;
    }

    // fused LN_s + (u | gate) GEMM: A = x directly
    k_gemm128<4, true, false><<<128 * 12, 256, 0, stream>>>(
        (const short*)x, (const short*)wigT, b_in + l * D_MOD, b_gate + l * D_MOD,
        wvig + (size_t)l * 2 * D_MOD, bvig + (size_t)l * 2 * D_MOD,
        statslot(2 * l), nullptr, nullptr, u, gate, 2 * D_MOD, D_MOD, 12);
    // chunked scan; s*gate -> gate buffer (bf16)
    k_scan_a<<<S_G, 192, 0, stream>>>((const bf16*)u, dlogit + l * D_MOD, clast);
    k_scan_b<<<1, D_MOD, 0, stream>>>(clast, dlogit + l * D_MOD, carry);
    k_scan_c<<<S_G, 192, 0, stream>>>((const bf16*)u, dlogit + l * D_MOD, carry, (bf16*)gate);
    // x = x + sg @ W_out + b_out  (bf16 in-place + stats slot 2l+1)
    k_gemm128<3, false, true><<<128 * 6, 256, 0, stream>>>(
        (const short*)gate, (const short*)woT, b_out + l * D_MOD, nullptr, nullptr, nullptr,
        nullptr, statslot(2 * l + 1), x, x, nullptr, D_MOD, D_MOD, 6);
    // fused LN_f + FF1 (silu): A = x directly
    k_gemm128<2, true, false><<<128 * 12, 256, 0, stream>>>(
        (const short*)x, (const short*)wf1T, b_ff1 + l * D_FF, nullptr,
        wvf1 + (size_t)l * D_FF, bvf1 + (size_t)l * D_FF,
        statslot(2 * l + 1), nullptr, nullptr, tb, nullptr, D_FF, D_MOD, 12);
    // x = x + tb @ W_ff2 + b_ff2  (bf16 in-place + stats slot 2l+2)
    k_gemm128<3, false, true><<<128 * 6, 256, 0, stream>>>(
        (const short*)tb, (const short*)wf2T, b_ff2 + l * D_MOD, nullptr, nullptr, nullptr,
        nullptr, statslot(2 * l + 2), x, x, nullptr, D_MOD, D_FF, 6);
  }

  // out = LN_o(x) (f32) using stats slot 16
  k_ln_final<<<L_TOK / 4, 256, 0, stream>>>(x, statslot(2 * N_LAYER), ln_o_g, ln_o_b, (float*)d_out);
}